// Round 2
// baseline (263.573 us; speedup 1.0000x reference)
//
#include <hip/hip_runtime.h>
#include <math.h>

#define BATCH 2
#define SEQ 2048
#define DMODEL 1024
#define HEADS 16
#define HSIZE 64
#define FREQS 256
#define NH 1024
#define QKVN 3072

typedef __bf16 bf16;
typedef __bf16 bf16x8 __attribute__((ext_vector_type(8)));
typedef float f32x4 __attribute__((ext_vector_type(4)));

static __device__ __forceinline__ unsigned short bf16_bits(float v) {
    bf16 b = (bf16)v; return __builtin_bit_cast(unsigned short, b);
}

// async global->LDS, 16 bytes per lane; LDS dest = wave-uniform base + lane*16
static __device__ __forceinline__ void gload16(const void* g, void* l) {
    __builtin_amdgcn_global_load_lds(
        (const __attribute__((address_space(1))) unsigned int*)g,
        (__attribute__((address_space(3))) unsigned int*)l, 16, 0, 0);
}

// ---------------------------------------------------------------------------
// Merged prep: fp32->bf16 cast of input, fp64 sinusoid table, and the three
// weight transpose+casts, decoded from a 1D block range. One launch.
// ---------------------------------------------------------------------------
__global__ __launch_bounds__(256) void prep_kernel(
    const float* __restrict__ inp, const float* __restrict__ qkv_w,
    const float* __restrict__ out_kernel, const float* __restrict__ positional,
    bf16* __restrict__ a_bf, bf16* __restrict__ wt_qkv,
    bf16* __restrict__ wt_out, bf16* __restrict__ wt_pos,
    bf16* __restrict__ sins_bf)
{
    __shared__ float tile[32][33];
    const int id = blockIdx.x, t = threadIdx.x;

    if (id < 4096) {            // input cast
        int i = id * 256 + t;
        float4 v = ((const float4*)inp)[i];
        ushort4 o;
        o.x = bf16_bits(v.x); o.y = bf16_bits(v.y);
        o.z = bf16_bits(v.z); o.w = bf16_bits(v.w);
        ((ushort4*)a_bf)[i] = o;
        return;
    }
    if (id < 6144) {            // sinusoid table (fp64, matches numpy)
        int i = (id - 4096) * 256 + t;
        int s = i >> 8, f = i & 255;
        double e = -(double)((f >> 1) << 1) / (double)FREQS;
        double invf = pow(10000.0, e);
        double ang = (double)s * invf;
        double v = (f & 1) ? cos(ang) : sin(ang);
        sins_bf[i] = (bf16)(float)(1.4142135623730951 * v);
        return;
    }
    int id2 = id - 6144;
    const float* src; bf16* dst; int R, C, c0, r0;
    if (id2 < 3072) {
        src = qkv_w; dst = wt_qkv; R = 1024; C = 3072;
        c0 = (id2 % 96) * 32; r0 = (id2 / 96) * 32;
    } else if (id2 < 4096) {
        id2 -= 3072;
        src = out_kernel; dst = wt_out; R = 1024; C = 1024;
        c0 = (id2 & 31) * 32; r0 = (id2 >> 5) * 32;
    } else {
        id2 -= 4096;
        src = positional; dst = wt_pos; R = 256; C = 1024;
        c0 = (id2 & 31) * 32; r0 = (id2 >> 5) * 32;
    }
    const int tx = t & 31, ty = t >> 5;
#pragma unroll
    for (int i = 0; i < 4; i++)
        tile[ty + i * 8][tx] = src[(size_t)(r0 + ty + i * 8) * C + c0 + tx];
    __syncthreads();
#pragma unroll
    for (int i = 0; i < 4; i++)
        dst[(size_t)(c0 + ty + i * 8) * R + r0 + tx] = (bf16)tile[tx][ty + i * 8];
}

// ---------------------------------------------------------------------------
// Pipelined bf16 MFMA GEMM: C[M][N] = A[M][K] @ Bt[N][K]^T, 128x128 tile,
// BK=32, double-buffered LDS, one barrier per K-iter (prefetch overlaps MFMA).
// EPI 0: out-proj fp32 = acc*alpha + bias[col]
// EPI 1: merged QKV+emb dispatch (see round notes).
// ---------------------------------------------------------------------------
template<int EPI>
__global__ __launch_bounds__(256) void mfma_gemm(
    const bf16* __restrict__ A, const bf16* __restrict__ Bt,
    int K, float alpha, const float* __restrict__ bias,
    float* __restrict__ outf, bf16* __restrict__ ob0, bf16* __restrict__ ob1,
    bf16* __restrict__ ob2,
    const bf16* __restrict__ A2, const bf16* __restrict__ Bt2,
    bf16* __restrict__ ob3, float alpha2)
{
    __shared__ __align__(16) bf16 Atile[2][128 * 32];
    __shared__ __align__(16) bf16 Btile[2][128 * 32];

    const int t    = threadIdx.x;
    const int lane = t & 63;
    const int w    = t >> 6;
    const int quad = lane >> 4;
    const int l16  = lane & 15;
    const int wm   = (w >> 1) * 64;
    const int wn   = (w & 1) * 64;

    bool embp = false;
    int m0 = blockIdx.y * 128, n0 = blockIdx.x * 128, Kl = K;
    const bf16* Ap = A; const bf16* Btp = Bt; float al = alpha;
    if constexpr (EPI == 1) {
        if (blockIdx.x >= 24) {
            if (blockIdx.y >= 16) return;   // emb has only 2048 rows
            embp = true;
            n0 = (blockIdx.x - 24) * 128;
            Kl = FREQS; Ap = A2; Btp = Bt2; al = alpha2;
        }
    }
    const bool swapv = (EPI == 1) && !embp && (n0 >= 2048);

    // staging coords (16B chunk swizzle)
    const int rS = t >> 2;
    const int cS = (t & 3) ^ ((rS >> 1) & 3);
    const bf16* ag0 = Ap  + (size_t)(m0 + rS) * Kl + cS * 8;
    const bf16* ag1 = ag0 + (size_t)64 * Kl;
    const bf16* bg0 = Btp + (size_t)(n0 + rS) * Kl + cS * 8;
    const bf16* bg1 = bg0 + (size_t)64 * Kl;

    // fragment LDS offsets (within one buffer)
    int aoff[4], boff[4];
#pragma unroll
    for (int mi = 0; mi < 4; ++mi) {
        int r = wm + mi * 16 + l16;
        aoff[mi] = r * 32 + ((quad ^ ((r >> 1) & 3)) * 8);
    }
#pragma unroll
    for (int ni = 0; ni < 4; ++ni) {
        int r = wn + ni * 16 + l16;
        boff[ni] = r * 32 + ((quad ^ ((r >> 1) & 3)) * 8);
    }

    // preload chunk 0 into buffer 0
    gload16(ag0, (char*)Atile[0] + t * 16);
    gload16(ag1, (char*)Atile[0] + 4096 + t * 16);
    gload16(bg0, (char*)Btile[0] + t * 16);
    gload16(bg1, (char*)Btile[0] + 4096 + t * 16);

    const int nK = Kl >> 5;
    f32x4 acc[4][4] = {};

    for (int kk = 0; kk < nK; ++kk) {
        __syncthreads();     // drains prefetch for kk (vmcnt) + prev reads
        if (kk + 1 < nK) {   // prefetch kk+1 into alternate buffer
            ag0 += 32; ag1 += 32; bg0 += 32; bg1 += 32;
            char* ad = (char*)Atile[(kk + 1) & 1];
            char* bd = (char*)Btile[(kk + 1) & 1];
            gload16(ag0, ad + t * 16); gload16(ag1, ad + 4096 + t * 16);
            gload16(bg0, bd + t * 16); gload16(bg1, bd + 4096 + t * 16);
        }
        const bf16* ab = Atile[kk & 1];
        const bf16* bb = Btile[kk & 1];
        bf16x8 af[4], bfr[4];
#pragma unroll
        for (int mi = 0; mi < 4; ++mi) af[mi] = *(const bf16x8*)(ab + aoff[mi]);
#pragma unroll
        for (int ni = 0; ni < 4; ++ni) bfr[ni] = *(const bf16x8*)(bb + boff[ni]);

        if (!swapv) {
#pragma unroll
            for (int mi = 0; mi < 4; ++mi)
#pragma unroll
                for (int ni = 0; ni < 4; ++ni)
                    acc[mi][ni] = __builtin_amdgcn_mfma_f32_16x16x32_bf16(
                        af[mi], bfr[ni], acc[mi][ni], 0, 0, 0);
        } else {
#pragma unroll
            for (int mi = 0; mi < 4; ++mi)
#pragma unroll
                for (int ni = 0; ni < 4; ++ni)
                    acc[mi][ni] = __builtin_amdgcn_mfma_f32_16x16x32_bf16(
                        bfr[ni], af[mi], acc[mi][ni], 0, 0, 0);
        }
    }

    if constexpr (EPI == 0) {
#pragma unroll
        for (int mi = 0; mi < 4; ++mi)
#pragma unroll
            for (int ni = 0; ni < 4; ++ni) {
                int col = n0 + wn + ni * 16 + l16;
                float bb = bias[col];
#pragma unroll
                for (int rg = 0; rg < 4; ++rg) {
                    int row = m0 + wm + mi * 16 + quad * 4 + rg;
                    outf[(size_t)row * NH + col] = acc[mi][ni][rg] * al + bb;
                }
            }
    } else {
        if (embp) {  // embT[head][d][h'] chunk-swizzled by (d+63)&7
#pragma unroll
            for (int mi = 0; mi < 4; ++mi)
#pragma unroll
                for (int ni = 0; ni < 4; ++ni) {
                    int col = n0 + wn + ni * 16 + l16;
                    int head = col >> 6, h = col & 63;
#pragma unroll
                    for (int rg = 0; rg < 4; ++rg) {
                        int d = m0 + wm + mi * 16 + quad * 4 + rg;
                        int hs = h ^ (((d + 63) & 7) << 3);
                        ob3[((size_t)(head * SEQ + d)) * 64 + hs] =
                            (bf16)(acc[mi][ni][rg] * al);
                    }
                }
        } else if (n0 >= 2048) {
            // swapped: acc rows = head-cols, cols = seq-rows -> Vt swizzled
#pragma unroll
            for (int mi = 0; mi < 4; ++mi)
#pragma unroll
                for (int ni = 0; ni < 4; ++ni) {
                    int mcol = m0 + wm + mi * 16 + l16;
                    int bb = mcol >> 11, s = mcol & 2047;
#pragma unroll
                    for (int rg = 0; rg < 4; ++rg) {
                        int hg = n0 + wn + ni * 16 + quad * 4 + rg;
                        int head = (hg & 1023) >> 6, h = hg & 63;
                        int ss = s ^ ((h & 7) << 3);
                        ob2[((size_t)((bb * 16 + head) * 64 + h)) * SEQ + ss] =
                            (bf16)(acc[mi][ni][rg] * al);
                    }
                }
        } else {
            const int whichk = (n0 >= 1024);
#pragma unroll
            for (int mi = 0; mi < 4; ++mi)
#pragma unroll
                for (int ni = 0; ni < 4; ++ni) {
                    int cg   = (n0 + wn + ni * 16 + l16) & 1023;
                    int head = cg >> 6, h = cg & 63;
                    float qbv = whichk ? 0.0f : bias[cg];
#pragma unroll
                    for (int rg = 0; rg < 4; ++rg) {
                        int row = m0 + wm + mi * 16 + quad * 4 + rg;
                        int bb = row >> 11, s = row & 2047;
                        float v = acc[mi][ni][rg] * al;
                        if (whichk) {
                            int hs = h ^ ((s & 7) << 3);
                            ob1[((size_t)((bb * 16 + head) * SEQ + s)) * 64 + hs] = (bf16)v;
                        } else {
                            ob0[((size_t)((bb * 16 + head) * SEQ + s)) * 64 + h] =
                                (bf16)((v + qbv) * 0.125f);
                        }
                    }
                }
        }
    }
}

// ---------------------------------------------------------------------------
// MFMA flash attention v6: 128-row Q tile, double-buffered K/V prefetch,
// 256-row Es ring, one barrier per k-tile, no-max softmax, ds_permute
// diagonal gather.  Changes vs v5:
//  - last k-tile PEELED out of the main loop: steady-state body is a single
//    basic block (the `if (c==0 && last) continue` branch previously blocked
//    cross-half instruction scheduling)
//  - phases hand-ordered so c1's QK/pos MFMAs cover c0's PS LDS round-trip,
//    and c1's E-reads are queued ahead of the PS writes
//  - s_setprio(1) around MFMA clusters (T5)
// ---------------------------------------------------------------------------
__global__ __launch_bounds__(256, 2) void attn_kernel(
    const bf16* __restrict__ Qb, const bf16* __restrict__ Kb,
    const bf16* __restrict__ Vtb, const bf16* __restrict__ Eb,
    bf16* __restrict__ o)
{
    __shared__ __align__(16) bf16 Ks[2][4096];
    __shared__ __align__(16) bf16 Vts[2][4096];
    __shared__ __align__(16) bf16 Es[256 * 64];
    __shared__ __align__(16) bf16 PS[4][16][72];

    const int t    = threadIdx.x;
    const int lane = t & 63;
    const int w    = t >> 6;
    const int quad = lane >> 4;
    const int l16  = lane & 15;

    const int bx = blockIdx.x;
    const int b  = bx >> 4, n = bx & 15;
    const int yy = blockIdx.y;
    const int qc = (yy < 8) ? (15 - 2 * yy) : (2 * yy - 16);
    const int q0 = qc * 128;
    const int KT = 2 * qc + 2;
    const int qw0 = q0 + 16 * w;
    const int qw1 = qw0 + 64;

    const bf16* __restrict__ Qp = Qb  + (size_t)bx * SEQ * 64;
    const bf16* __restrict__ Kp = Kb  + (size_t)bx * SEQ * 64;
    const bf16* __restrict__ Vp = Vtb + (size_t)bx * SEQ * 64;
    const bf16* __restrict__ Ep = Eb  + (size_t)n  * SEQ * 64;

    const int key8 = (l16 & 7) << 3;
    const int ec0  = ((quad * 8) ^ key8) * 2;
    const int ec1  = ((32 + quad * 8) ^ key8) * 2;

    bf16x8 qf[2][2];
    qf[0][0] = *(const bf16x8*)(Qp + (size_t)(qw0 + l16) * 64 + quad * 8);
    qf[0][1] = *(const bf16x8*)(Qp + (size_t)(qw0 + l16) * 64 + 32 + quad * 8);
    qf[1][0] = *(const bf16x8*)(Qp + (size_t)(qw1 + l16) * 64 + quad * 8);
    qf[1][1] = *(const bf16x8*)(Qp + (size_t)(qw1 + l16) * 64 + 32 + quad * 8);

    int dsta[4];
    bool condp[4];
#pragma unroll
    for (int rg = 0; rg < 4; ++rg) {
        int rr   = quad * 4 + rg;
        int l16c = (rr + 15 - l16) & 15;
        dsta[rg]  = ((lane & 48) + l16c) << 2;
        condp[rg] = rr > l16c;
    }

    f32x4 O[2][4] = {};
    float lsum[2][4] = {};

    {
        gload16(Kp + t * 8,        (char*)Ks[0] + t * 16);
        gload16(Kp + 2048 + t * 8, (char*)Ks[0] + 4096 + t * 16);
        gload16(Vp + (size_t)(t >> 3) * SEQ + (t & 7) * 8,        (char*)Vts[0] + t * 16);
        gload16(Vp + (size_t)((t >> 3) + 32) * SEQ + (t & 7) * 8, (char*)Vts[0] + 4096 + t * 16);
        const long D0 = (long)q0 - 63;
#pragma unroll
        for (int g = 0; g < 6; ++g)
            gload16(Ep + (D0 + 32 * g) * 64 + t * 8, (char*)Es + g * 4096 + t * 16);
    }

    // ---- phase helpers (all indices compile-time after inlining) ----
    auto load_kv = [&](const char* kb, const char* vb,
                       bf16x8 (&kf)[4][2], bf16x8 (&vf)[4][2]) {
#pragma unroll
        for (int j = 0; j < 4; ++j) {
            const char* kp = kb + (j * 16 + l16) * 128;
            kf[j][0] = *(const bf16x8*)(kp + ec0);
            kf[j][1] = *(const bf16x8*)(kp + ec1);
            const char* vp = vb + (j * 16 + l16) * 128;
            vf[j][0] = *(const bf16x8*)(vp + ec0);
            vf[j][1] = *(const bf16x8*)(vp + ec1);
        }
    };
    auto eread = [&](int rb, bf16x8 (&ef)[5][2]) {
#pragma unroll
        for (int jj = 0; jj < 5; ++jj) {
            const char* ep = (const char*)Es + ((rb + 16 * jj + l16) & 255) * 128;
            ef[jj][0] = *(const bf16x8*)(ep + ec0);
            ef[jj][1] = *(const bf16x8*)(ep + ec1);
        }
    };
    auto qkmfma = [&](const bf16x8 (&q2)[2], const bf16x8 (&kf)[4][2],
                      f32x4 (&S)[4]) {
#pragma unroll
        for (int j = 0; j < 4; ++j) {
            f32x4 a = {0, 0, 0, 0};
            a = __builtin_amdgcn_mfma_f32_16x16x32_bf16(q2[1], kf[j][1], a, 0, 0, 0);
            a = __builtin_amdgcn_mfma_f32_16x16x32_bf16(q2[0], kf[j][0], a, 0, 0, 0);
            S[j] = a;
        }
    };
    auto pamfma = [&](const bf16x8 (&q2)[2], const bf16x8 (&ef)[5][2],
                      f32x4 (&pa)[5]) {
#pragma unroll
        for (int jj = 0; jj < 5; ++jj) {
            f32x4 a = {0, 0, 0, 0};
            a = __builtin_amdgcn_mfma_f32_16x16x32_bf16(q2[1], ef[jj][1], a, 0, 0, 0);
            a = __builtin_amdgcn_mfma_f32_16x16x32_bf16(q2[0], ef[jj][0], a, 0, 0, 0);
            pa[jj] = a;
        }
    };
    auto smax = [&](int kq, f32x4 (&S)[4], const f32x4 (&pa)[5], float (&ls)[4]) {
#pragma unroll
        for (int j = 0; j < 4; ++j) {
#pragma unroll
            for (int rg = 0; rg < 4; ++rg) {
                float vsel = condp[rg] ? pa[4 - j][rg] : pa[3 - j][rg];
                int pv = __builtin_amdgcn_ds_permute(dsta[rg], __float_as_int(vsel));
                float sv = S[j][rg] + __int_as_float(pv);
                bool valid = (j * 16 + l16) <= (kq + quad * 4 + rg);
                S[j][rg] = valid ? __expf(sv) : 0.0f;
            }
        }
#pragma unroll
        for (int rg = 0; rg < 4; ++rg)
            ls[rg] += S[0][rg] + S[1][rg] + S[2][rg] + S[3][rg];
    };
    auto ps_write = [&](const f32x4 (&S)[4]) {
#pragma unroll
        for (int j = 0; j < 4; ++j)
#pragma unroll
            for (int rg = 0; rg < 4; ++rg)
                PS[w][quad * 4 + rg][j * 16 + l16] = (bf16)S[j][rg];
    };
    auto pvmfma = [&](const bf16x8 (&vf)[4][2], f32x4 (&Oc)[4]) {
        bf16x8 pf0 = *(const bf16x8*)(&PS[w][l16][quad * 8]);
        bf16x8 pf1 = *(const bf16x8*)(&PS[w][l16][32 + quad * 8]);
#pragma unroll
        for (int j4 = 0; j4 < 4; ++j4) {
            Oc[j4] = __builtin_amdgcn_mfma_f32_16x16x32_bf16(pf1, vf[j4][1], Oc[j4], 0, 0, 0);
            Oc[j4] = __builtin_amdgcn_mfma_f32_16x16x32_bf16(pf0, vf[j4][0], Oc[j4], 0, 0, 0);
        }
    };

    // ---- steady state: all tiles except the last; branch-free body ----
    for (int kt = 0; kt < KT - 1; ++kt) {
        const int k0 = kt * 64;
        __syncthreads();

        {   // prefetch kt+1 (always exists here)
            const int nt = kt + 1;
            bf16* kd = Ks[nt & 1];
            bf16* vd = Vts[nt & 1];
            const bf16* ksrc = Kp + nt * 4096;
            gload16(ksrc + t * 8,        (char*)kd + t * 16);
            gload16(ksrc + 2048 + t * 8, (char*)kd + 4096 + t * 16);
            gload16(Vp + (size_t)(t >> 3) * SEQ + nt * 64 + (t & 7) * 8,
                    (char*)vd + t * 16);
            gload16(Vp + (size_t)((t >> 3) + 32) * SEQ + nt * 64 + (t & 7) * 8,
                    (char*)vd + 4096 + t * 16);
            const long d0 = (long)q0 - nt * 64 - 63;
            const int rI = (-64 * nt) & 255;
            gload16(Ep + d0 * 64 + t * 8,        (char*)Es + rI * 128 + t * 16);
            gload16(Ep + (d0 + 32) * 64 + t * 8, (char*)Es + rI * 128 + 4096 + t * 16);
        }

        bf16x8 kf[4][2], vf[4][2];
        load_kv((const char*)Ks[kt & 1], (const char*)Vts[kt & 1], kf, vf);

        // c0: scores
        bf16x8 ef0[5][2];
        eread(16 * w - k0, ef0);
        f32x4 S0[4], pa0[5];
        __builtin_amdgcn_s_setprio(1);
        qkmfma(qf[0], kf, S0);
        pamfma(qf[0], ef0, pa0);
        __builtin_amdgcn_s_setprio(0);
        smax(qw0 - k0, S0, pa0, lsum[0]);

        // queue c1's E reads ahead of the PS writes, then write P(c0)
        bf16x8 ef1[5][2];
        eread(16 * w + 64 - k0, ef1);
        ps_write(S0);

        // c1 scores overlap c0's PS round-trip; then PV(c0)
        f32x4 S1[4], pa1[5];
        __builtin_amdgcn_s_setprio(1);
        qkmfma(qf[1], kf, S1);
        pamfma(qf[1], ef1, pa1);
        pvmfma(vf, O[0]);
        __builtin_amdgcn_s_setprio(0);

        smax(qw1 - k0, S1, pa1, lsum[1]);
        ps_write(S1);
        __builtin_amdgcn_s_setprio(1);
        pvmfma(vf, O[1]);
        __builtin_amdgcn_s_setprio(0);
    }

    // ---- peeled last tile: lower half (c0) is fully masked, skip it ----
    {
        const int kt = KT - 1, k0 = kt * 64;
        __syncthreads();
        bf16x8 kf[4][2], vf[4][2];
        load_kv((const char*)Ks[kt & 1], (const char*)Vts[kt & 1], kf, vf);
        bf16x8 ef1[5][2];
        eread(16 * w + 64 - k0, ef1);
        f32x4 S1[4], pa1[5];
        qkmfma(qf[1], kf, S1);
        pamfma(qf[1], ef1, pa1);
        smax(qw1 - k0, S1, pa1, lsum[1]);
        ps_write(S1);
        pvmfma(vf, O[1]);
    }

#pragma unroll
    for (int c = 0; c < 2; ++c) {
#pragma unroll
        for (int rg = 0; rg < 4; ++rg) {
            float s = lsum[c][rg];
            s += __shfl_xor(s, 1);
            s += __shfl_xor(s, 2);
            s += __shfl_xor(s, 4);
            s += __shfl_xor(s, 8);
            float inv = 1.0f / s;
            int q = (c ? qw1 : qw0) + quad * 4 + rg;
            size_t ro = ((size_t)(b * SEQ + q)) * NH + n * 64;
            o[ro +  0 + l16] = (bf16)(O[c][0][rg] * inv);
            o[ro + 16 + l16] = (bf16)(O[c][1][rg] * inv);
            o[ro + 32 + l16] = (bf16)(O[c][2][rg] * inv);
            o[ro + 48 + l16] = (bf16)(O[c][3][rg] * inv);
        }
    }
}

// ---------------------------------------------------------------------------
extern "C" void kernel_launch(void* const* d_in, const int* in_sizes, int n_in,
                              void* d_out, int out_size, void* d_ws, size_t ws_size,
                              hipStream_t stream) {
    const float* inp        = (const float*)d_in[0];
    const float* qkv_w      = (const float*)d_in[1];
    const float* q_bias     = (const float*)d_in[2];
    const float* positional = (const float*)d_in[3];
    const float* out_kernel = (const float*)d_in[4];
    const float* out_bias   = (const float*)d_in[5];

    char* p = (char*)d_ws;
    auto alloc = [&](size_t bytes) {
        char* q = p; p += (bytes + 255) & ~(size_t)255; return q;
    };
    bf16* qbuf    = (bf16*)alloc((size_t)BATCH * HEADS * SEQ * HSIZE * 2);
    bf16* kbuf    = (bf16*)alloc((size_t)BATCH * HEADS * SEQ * HSIZE * 2);
    bf16* vtbuf   = (bf16*)alloc((size_t)BATCH * HEADS * SEQ * HSIZE * 2);
    bf16* embT    = (bf16*)alloc((size_t)HEADS * SEQ * HSIZE * 2);  // after vtbuf (negative-d slack)
    bf16* sins_bf = (bf16*)alloc((size_t)SEQ * FREQS * 2);          // after embT (d>=2048 slack)
    bf16* obuf    = (bf16*)alloc((size_t)BATCH * SEQ * NH * 2);
    bf16* a_bf    = (bf16*)alloc((size_t)BATCH * SEQ * DMODEL * 2);
    bf16* wt_qkv  = (bf16*)alloc((size_t)QKVN * DMODEL * 2);
    bf16* wt_out  = (bf16*)alloc((size_t)NH * DMODEL * 2);
    bf16* wt_pos  = (bf16*)alloc((size_t)NH * FREQS * 2);

    const float qkv_scale = (float)pow(3.0 * DMODEL * HSIZE * HEADS, -0.25);
    const float emb_scale = 0.0625f;   // 256^-0.5
    const float out_scale = 0.03125f;  // (1024*1024)^-0.25

    // 1. merged prep (cast + sins + 3 transposes)
    prep_kernel<<<10496, 256, 0, stream>>>(
        inp, qkv_w, out_kernel, positional, a_bf, wt_qkv, wt_out, wt_pos, sins_bf);

    // 2. merged QKV projection + emb GEMM
    mfma_gemm<1><<<dim3(32, 32), 256, 0, stream>>>(
        a_bf, wt_qkv, DMODEL, qkv_scale, q_bias, nullptr, qbuf, kbuf, vtbuf,
        sins_bf, wt_pos, embT, emb_scale);

    // 3. flash attention -> bf16 o
    attn_kernel<<<dim3(32, 16), 256, 0, stream>>>(
        qbuf, kbuf, vtbuf, embT, obuf);

    // 4. output projection (fp32 out)
    mfma_gemm<0><<<dim3(8, 32), 256, 0, stream>>>(
        obuf, wt_out, DMODEL, out_scale, out_bias, (float*)d_out,
        nullptr, nullptr, nullptr, nullptr, nullptr, nullptr, 0.0f);
}

// Round 3
// 259.068 us; speedup vs baseline: 1.0174x; 1.0174x over previous
//
#include <hip/hip_runtime.h>
#include <math.h>

#define BATCH 2
#define SEQ 2048
#define DMODEL 1024
#define HEADS 16
#define HSIZE 64
#define FREQS 256
#define NH 1024
#define QKVN 3072

typedef __bf16 bf16;
typedef __bf16 bf16x8 __attribute__((ext_vector_type(8)));
typedef float f32x4 __attribute__((ext_vector_type(4)));

static __device__ __forceinline__ unsigned short bf16_bits(float v) {
    bf16 b = (bf16)v; return __builtin_bit_cast(unsigned short, b);
}

// async global->LDS, 16 bytes per lane; LDS dest = wave-uniform base + lane*16
static __device__ __forceinline__ void gload16(const void* g, void* l) {
    __builtin_amdgcn_global_load_lds(
        (const __attribute__((address_space(1))) unsigned int*)g,
        (__attribute__((address_space(3))) unsigned int*)l, 16, 0, 0);
}

// ---------------------------------------------------------------------------
// Merged prep: fp32->bf16 cast of input, fp64 sinusoid table, and the three
// weight transpose+casts, decoded from a 1D block range. One launch.
// ---------------------------------------------------------------------------
__global__ __launch_bounds__(256) void prep_kernel(
    const float* __restrict__ inp, const float* __restrict__ qkv_w,
    const float* __restrict__ out_kernel, const float* __restrict__ positional,
    bf16* __restrict__ a_bf, bf16* __restrict__ wt_qkv,
    bf16* __restrict__ wt_out, bf16* __restrict__ wt_pos,
    bf16* __restrict__ sins_bf)
{
    __shared__ float tile[32][33];
    const int id = blockIdx.x, t = threadIdx.x;

    if (id < 4096) {            // input cast
        int i = id * 256 + t;
        float4 v = ((const float4*)inp)[i];
        ushort4 o;
        o.x = bf16_bits(v.x); o.y = bf16_bits(v.y);
        o.z = bf16_bits(v.z); o.w = bf16_bits(v.w);
        ((ushort4*)a_bf)[i] = o;
        return;
    }
    if (id < 6144) {            // sinusoid table (fp64, matches numpy)
        int i = (id - 4096) * 256 + t;
        int s = i >> 8, f = i & 255;
        double e = -(double)((f >> 1) << 1) / (double)FREQS;
        double invf = pow(10000.0, e);
        double ang = (double)s * invf;
        double v = (f & 1) ? cos(ang) : sin(ang);
        sins_bf[i] = (bf16)(float)(1.4142135623730951 * v);
        return;
    }
    int id2 = id - 6144;
    const float* src; bf16* dst; int R, C, c0, r0;
    if (id2 < 3072) {
        src = qkv_w; dst = wt_qkv; R = 1024; C = 3072;
        c0 = (id2 % 96) * 32; r0 = (id2 / 96) * 32;
    } else if (id2 < 4096) {
        id2 -= 3072;
        src = out_kernel; dst = wt_out; R = 1024; C = 1024;
        c0 = (id2 & 31) * 32; r0 = (id2 >> 5) * 32;
    } else {
        id2 -= 4096;
        src = positional; dst = wt_pos; R = 256; C = 1024;
        c0 = (id2 & 31) * 32; r0 = (id2 >> 5) * 32;
    }
    const int tx = t & 31, ty = t >> 5;
#pragma unroll
    for (int i = 0; i < 4; i++)
        tile[ty + i * 8][tx] = src[(size_t)(r0 + ty + i * 8) * C + c0 + tx];
    __syncthreads();
#pragma unroll
    for (int i = 0; i < 4; i++)
        dst[(size_t)(c0 + ty + i * 8) * R + r0 + tx] = (bf16)tile[tx][ty + i * 8];
}

// ---------------------------------------------------------------------------
// Pipelined bf16 MFMA GEMM (unchanged).
// ---------------------------------------------------------------------------
template<int EPI>
__global__ __launch_bounds__(256) void mfma_gemm(
    const bf16* __restrict__ A, const bf16* __restrict__ Bt,
    int K, float alpha, const float* __restrict__ bias,
    float* __restrict__ outf, bf16* __restrict__ ob0, bf16* __restrict__ ob1,
    bf16* __restrict__ ob2,
    const bf16* __restrict__ A2, const bf16* __restrict__ Bt2,
    bf16* __restrict__ ob3, float alpha2)
{
    __shared__ __align__(16) bf16 Atile[2][128 * 32];
    __shared__ __align__(16) bf16 Btile[2][128 * 32];

    const int t    = threadIdx.x;
    const int lane = t & 63;
    const int w    = t >> 6;
    const int quad = lane >> 4;
    const int l16  = lane & 15;
    const int wm   = (w >> 1) * 64;
    const int wn   = (w & 1) * 64;

    bool embp = false;
    int m0 = blockIdx.y * 128, n0 = blockIdx.x * 128, Kl = K;
    const bf16* Ap = A; const bf16* Btp = Bt; float al = alpha;
    if constexpr (EPI == 1) {
        if (blockIdx.x >= 24) {
            if (blockIdx.y >= 16) return;   // emb has only 2048 rows
            embp = true;
            n0 = (blockIdx.x - 24) * 128;
            Kl = FREQS; Ap = A2; Btp = Bt2; al = alpha2;
        }
    }
    const bool swapv = (EPI == 1) && !embp && (n0 >= 2048);

    // staging coords (16B chunk swizzle)
    const int rS = t >> 2;
    const int cS = (t & 3) ^ ((rS >> 1) & 3);
    const bf16* ag0 = Ap  + (size_t)(m0 + rS) * Kl + cS * 8;
    const bf16* ag1 = ag0 + (size_t)64 * Kl;
    const bf16* bg0 = Btp + (size_t)(n0 + rS) * Kl + cS * 8;
    const bf16* bg1 = bg0 + (size_t)64 * Kl;

    // fragment LDS offsets (within one buffer)
    int aoff[4], boff[4];
#pragma unroll
    for (int mi = 0; mi < 4; ++mi) {
        int r = wm + mi * 16 + l16;
        aoff[mi] = r * 32 + ((quad ^ ((r >> 1) & 3)) * 8);
    }
#pragma unroll
    for (int ni = 0; ni < 4; ++ni) {
        int r = wn + ni * 16 + l16;
        boff[ni] = r * 32 + ((quad ^ ((r >> 1) & 3)) * 8);
    }

    // preload chunk 0 into buffer 0
    gload16(ag0, (char*)Atile[0] + t * 16);
    gload16(ag1, (char*)Atile[0] + 4096 + t * 16);
    gload16(bg0, (char*)Btile[0] + t * 16);
    gload16(bg1, (char*)Btile[0] + 4096 + t * 16);

    const int nK = Kl >> 5;
    f32x4 acc[4][4] = {};

    for (int kk = 0; kk < nK; ++kk) {
        __syncthreads();     // drains prefetch for kk (vmcnt) + prev reads
        if (kk + 1 < nK) {   // prefetch kk+1 into alternate buffer
            ag0 += 32; ag1 += 32; bg0 += 32; bg1 += 32;
            char* ad = (char*)Atile[(kk + 1) & 1];
            char* bd = (char*)Btile[(kk + 1) & 1];
            gload16(ag0, ad + t * 16); gload16(ag1, ad + 4096 + t * 16);
            gload16(bg0, bd + t * 16); gload16(bg1, bd + 4096 + t * 16);
        }
        const bf16* ab = Atile[kk & 1];
        const bf16* bb = Btile[kk & 1];
        bf16x8 af[4], bfr[4];
#pragma unroll
        for (int mi = 0; mi < 4; ++mi) af[mi] = *(const bf16x8*)(ab + aoff[mi]);
#pragma unroll
        for (int ni = 0; ni < 4; ++ni) bfr[ni] = *(const bf16x8*)(bb + boff[ni]);

        if (!swapv) {
#pragma unroll
            for (int mi = 0; mi < 4; ++mi)
#pragma unroll
                for (int ni = 0; ni < 4; ++ni)
                    acc[mi][ni] = __builtin_amdgcn_mfma_f32_16x16x32_bf16(
                        af[mi], bfr[ni], acc[mi][ni], 0, 0, 0);
        } else {
#pragma unroll
            for (int mi = 0; mi < 4; ++mi)
#pragma unroll
                for (int ni = 0; ni < 4; ++ni)
                    acc[mi][ni] = __builtin_amdgcn_mfma_f32_16x16x32_bf16(
                        bfr[ni], af[mi], acc[mi][ni], 0, 0, 0);
        }
    }

    if constexpr (EPI == 0) {
#pragma unroll
        for (int mi = 0; mi < 4; ++mi)
#pragma unroll
            for (int ni = 0; ni < 4; ++ni) {
                int col = n0 + wn + ni * 16 + l16;
                float bb = bias[col];
#pragma unroll
                for (int rg = 0; rg < 4; ++rg) {
                    int row = m0 + wm + mi * 16 + quad * 4 + rg;
                    outf[(size_t)row * NH + col] = acc[mi][ni][rg] * al + bb;
                }
            }
    } else {
        if (embp) {  // embT[head][d][h'] chunk-swizzled by (d+63)&7
#pragma unroll
            for (int mi = 0; mi < 4; ++mi)
#pragma unroll
                for (int ni = 0; ni < 4; ++ni) {
                    int col = n0 + wn + ni * 16 + l16;
                    int head = col >> 6, h = col & 63;
#pragma unroll
                    for (int rg = 0; rg < 4; ++rg) {
                        int d = m0 + wm + mi * 16 + quad * 4 + rg;
                        int hs = h ^ (((d + 63) & 7) << 3);
                        ob3[((size_t)(head * SEQ + d)) * 64 + hs] =
                            (bf16)(acc[mi][ni][rg] * al);
                    }
                }
        } else if (n0 >= 2048) {
            // swapped: acc rows = head-cols, cols = seq-rows -> Vt swizzled
#pragma unroll
            for (int mi = 0; mi < 4; ++mi)
#pragma unroll
                for (int ni = 0; ni < 4; ++ni) {
                    int mcol = m0 + wm + mi * 16 + l16;
                    int bb = mcol >> 11, s = mcol & 2047;
#pragma unroll
                    for (int rg = 0; rg < 4; ++rg) {
                        int hg = n0 + wn + ni * 16 + quad * 4 + rg;
                        int head = (hg & 1023) >> 6, h = hg & 63;
                        int ss = s ^ ((h & 7) << 3);
                        ob2[((size_t)((bb * 16 + head) * 64 + h)) * SEQ + ss] =
                            (bf16)(acc[mi][ni][rg] * al);
                    }
                }
        } else {
            const int whichk = (n0 >= 1024);
#pragma unroll
            for (int mi = 0; mi < 4; ++mi)
#pragma unroll
                for (int ni = 0; ni < 4; ++ni) {
                    int cg   = (n0 + wn + ni * 16 + l16) & 1023;
                    int head = cg >> 6, h = cg & 63;
                    float qbv = whichk ? 0.0f : bias[cg];
#pragma unroll
                    for (int rg = 0; rg < 4; ++rg) {
                        int row = m0 + wm + mi * 16 + quad * 4 + rg;
                        int bb = row >> 11, s = row & 2047;
                        float v = acc[mi][ni][rg] * al;
                        if (whichk) {
                            int hs = h ^ ((s & 7) << 3);
                            ob1[((size_t)((bb * 16 + head) * SEQ + s)) * 64 + hs] = (bf16)v;
                        } else {
                            ob0[((size_t)((bb * 16 + head) * SEQ + s)) * 64 + h] =
                                (bf16)((v + qbv) * 0.125f);
                        }
                    }
                }
        }
    }
}

// ---------------------------------------------------------------------------
// MFMA flash attention v7: v6 body + SPLIT-K load balancing.
// Work decomposition: qc<8 -> one block (full K range); qc>=8 -> two blocks,
// each half the K range. No-max softmax makes the merge additive: partials
// (unnormalized f32 O, lsum) are summed+normalized by merge_kernel.
// blockIdx.y ordered so the 512 heaviest blocks launch first (LPT backfill).
// ---------------------------------------------------------------------------
__device__ const unsigned char YQC[24]  = {15,15,7,14,14,13,13,6,12,12,11,11,
                                           5,10,10,9,9,4,8,8,3,2,1,0};
__device__ const unsigned char YPRT[24] = {0,1,2,0,1,0,1,2,0,1,0,1,
                                           2,0,1,0,1,2,0,1,2,2,2,2}; // 2=full

__global__ __launch_bounds__(256, 2) void attn_kernel(
    const bf16* __restrict__ Qb, const bf16* __restrict__ Kb,
    const bf16* __restrict__ Vtb, const bf16* __restrict__ Eb,
    bf16* __restrict__ o, float* __restrict__ Opart, float* __restrict__ Lpart)
{
    __shared__ __align__(16) bf16 Ks[2][4096];
    __shared__ __align__(16) bf16 Vts[2][4096];
    __shared__ __align__(16) bf16 Es[256 * 64];
    __shared__ __align__(16) bf16 PS[4][16][72];

    const int t    = threadIdx.x;
    const int lane = t & 63;
    const int w    = t >> 6;
    const int quad = lane >> 4;
    const int l16  = lane & 15;

    const int bx = blockIdx.x;
    const int b  = bx >> 4, n = bx & 15;
    const int yy = blockIdx.y;
    const int qc = YQC[yy];
    const int pr = YPRT[yy];
    const int q0 = qc * 128;
    const int KT = 2 * qc + 2;
    const int kt0 = (pr == 1) ? (qc + 1) : 0;
    const int kt1 = (pr == 0) ? (qc + 1) : KT;   // exclusive end of MY tiles
    const bool haspeel = (pr != 0);              // my range contains the diagonal tile
    const bool split   = (pr != 2);
    const int qw0 = q0 + 16 * w;
    const int qw1 = qw0 + 64;

    const bf16* __restrict__ Qp = Qb  + (size_t)bx * SEQ * 64;
    const bf16* __restrict__ Kp = Kb  + (size_t)bx * SEQ * 64;
    const bf16* __restrict__ Vp = Vtb + (size_t)bx * SEQ * 64;
    const bf16* __restrict__ Ep = Eb  + (size_t)n  * SEQ * 64;

    const int key8 = (l16 & 7) << 3;
    const int ec0  = ((quad * 8) ^ key8) * 2;
    const int ec1  = ((32 + quad * 8) ^ key8) * 2;

    bf16x8 qf[2][2];
    qf[0][0] = *(const bf16x8*)(Qp + (size_t)(qw0 + l16) * 64 + quad * 8);
    qf[0][1] = *(const bf16x8*)(Qp + (size_t)(qw0 + l16) * 64 + 32 + quad * 8);
    qf[1][0] = *(const bf16x8*)(Qp + (size_t)(qw1 + l16) * 64 + quad * 8);
    qf[1][1] = *(const bf16x8*)(Qp + (size_t)(qw1 + l16) * 64 + 32 + quad * 8);

    int dsta[4];
    bool condp[4];
#pragma unroll
    for (int rg = 0; rg < 4; ++rg) {
        int rr   = quad * 4 + rg;
        int l16c = (rr + 15 - l16) & 15;
        dsta[rg]  = ((lane & 48) + l16c) << 2;
        condp[rg] = rr > l16c;
    }

    f32x4 O[2][4] = {};
    float lsum[2][4] = {};

    {   // prologue: stage tile kt0 + the 192-row E window at ring phase rI0
        const bf16* ksrc = Kp + kt0 * 4096;
        char* kd = (char*)Ks[kt0 & 1];
        char* vd = (char*)Vts[kt0 & 1];
        gload16(ksrc + t * 8,        kd + t * 16);
        gload16(ksrc + 2048 + t * 8, kd + 4096 + t * 16);
        gload16(Vp + (size_t)(t >> 3) * SEQ + kt0 * 64 + (t & 7) * 8,        vd + t * 16);
        gload16(Vp + (size_t)((t >> 3) + 32) * SEQ + kt0 * 64 + (t & 7) * 8, vd + 4096 + t * 16);
        const long D0 = (long)q0 - 64 * kt0 - 63;
        const int rI0 = (-64 * kt0) & 255;
#pragma unroll
        for (int g = 0; g < 6; ++g) {
            const int sI = (rI0 + 32 * g) & 255;
            gload16(Ep + (D0 + 32 * g) * 64 + t * 8, (char*)Es + sI * 128 + t * 16);
        }
    }

    // ---- phase helpers ----
    auto load_kv = [&](const char* kb, const char* vb,
                       bf16x8 (&kf)[4][2], bf16x8 (&vf)[4][2]) {
#pragma unroll
        for (int j = 0; j < 4; ++j) {
            const char* kp = kb + (j * 16 + l16) * 128;
            kf[j][0] = *(const bf16x8*)(kp + ec0);
            kf[j][1] = *(const bf16x8*)(kp + ec1);
            const char* vp = vb + (j * 16 + l16) * 128;
            vf[j][0] = *(const bf16x8*)(vp + ec0);
            vf[j][1] = *(const bf16x8*)(vp + ec1);
        }
    };
    auto eread = [&](int rb, bf16x8 (&ef)[5][2]) {
#pragma unroll
        for (int jj = 0; jj < 5; ++jj) {
            const char* ep = (const char*)Es + ((rb + 16 * jj + l16) & 255) * 128;
            ef[jj][0] = *(const bf16x8*)(ep + ec0);
            ef[jj][1] = *(const bf16x8*)(ep + ec1);
        }
    };
    auto qkmfma = [&](const bf16x8 (&q2)[2], const bf16x8 (&kf)[4][2],
                      f32x4 (&S)[4]) {
#pragma unroll
        for (int j = 0; j < 4; ++j) {
            f32x4 a = {0, 0, 0, 0};
            a = __builtin_amdgcn_mfma_f32_16x16x32_bf16(q2[1], kf[j][1], a, 0, 0, 0);
            a = __builtin_amdgcn_mfma_f32_16x16x32_bf16(q2[0], kf[j][0], a, 0, 0, 0);
            S[j] = a;
        }
    };
    auto pamfma = [&](const bf16x8 (&q2)[2], const bf16x8 (&ef)[5][2],
                      f32x4 (&pa)[5]) {
#pragma unroll
        for (int jj = 0; jj < 5; ++jj) {
            f32x4 a = {0, 0, 0, 0};
            a = __builtin_amdgcn_mfma_f32_16x16x32_bf16(q2[1], ef[jj][1], a, 0, 0, 0);
            a = __builtin_amdgcn_mfma_f32_16x16x32_bf16(q2[0], ef[jj][0], a, 0, 0, 0);
            pa[jj] = a;
        }
    };
    auto smax = [&](int kq, f32x4 (&S)[4], const f32x4 (&pa)[5], float (&ls)[4]) {
#pragma unroll
        for (int j = 0; j < 4; ++j) {
#pragma unroll
            for (int rg = 0; rg < 4; ++rg) {
                float vsel = condp[rg] ? pa[4 - j][rg] : pa[3 - j][rg];
                int pv = __builtin_amdgcn_ds_permute(dsta[rg], __float_as_int(vsel));
                float sv = S[j][rg] + __int_as_float(pv);
                bool valid = (j * 16 + l16) <= (kq + quad * 4 + rg);
                S[j][rg] = valid ? __expf(sv) : 0.0f;
            }
        }
#pragma unroll
        for (int rg = 0; rg < 4; ++rg)
            ls[rg] += S[0][rg] + S[1][rg] + S[2][rg] + S[3][rg];
    };
    auto ps_write = [&](const f32x4 (&S)[4]) {
#pragma unroll
        for (int j = 0; j < 4; ++j)
#pragma unroll
            for (int rg = 0; rg < 4; ++rg)
                PS[w][quad * 4 + rg][j * 16 + l16] = (bf16)S[j][rg];
    };
    auto pvmfma = [&](const bf16x8 (&vf)[4][2], f32x4 (&Oc)[4]) {
        bf16x8 pf0 = *(const bf16x8*)(&PS[w][l16][quad * 8]);
        bf16x8 pf1 = *(const bf16x8*)(&PS[w][l16][32 + quad * 8]);
#pragma unroll
        for (int j4 = 0; j4 < 4; ++j4) {
            Oc[j4] = __builtin_amdgcn_mfma_f32_16x16x32_bf16(pf1, vf[j4][1], Oc[j4], 0, 0, 0);
            Oc[j4] = __builtin_amdgcn_mfma_f32_16x16x32_bf16(pf0, vf[j4][0], Oc[j4], 0, 0, 0);
        }
    };

    // ---- steady state over my tile range (minus peel if diagonal is mine) ----
    const int ktE = kt1 - (haspeel ? 1 : 0);
    for (int kt = kt0; kt < ktE; ++kt) {
        const int k0 = kt * 64;
        __syncthreads();

        const int nt = kt + 1;
        if (nt < kt1) {   // prefetch next tile of MY range
            bf16* kd = Ks[nt & 1];
            bf16* vd = Vts[nt & 1];
            const bf16* ksrc = Kp + nt * 4096;
            gload16(ksrc + t * 8,        (char*)kd + t * 16);
            gload16(ksrc + 2048 + t * 8, (char*)kd + 4096 + t * 16);
            gload16(Vp + (size_t)(t >> 3) * SEQ + nt * 64 + (t & 7) * 8,
                    (char*)vd + t * 16);
            gload16(Vp + (size_t)((t >> 3) + 32) * SEQ + nt * 64 + (t & 7) * 8,
                    (char*)vd + 4096 + t * 16);
            const long d0 = (long)q0 - nt * 64 - 63;
            const int rI = (-64 * nt) & 255;
            gload16(Ep + d0 * 64 + t * 8,        (char*)Es + rI * 128 + t * 16);
            gload16(Ep + (d0 + 32) * 64 + t * 8, (char*)Es + rI * 128 + 4096 + t * 16);
        }

        bf16x8 kf[4][2], vf[4][2];
        load_kv((const char*)Ks[kt & 1], (const char*)Vts[kt & 1], kf, vf);

        // c0: scores
        bf16x8 ef0[5][2];
        eread(16 * w - k0, ef0);
        f32x4 S0[4], pa0[5];
        __builtin_amdgcn_s_setprio(1);
        qkmfma(qf[0], kf, S0);
        pamfma(qf[0], ef0, pa0);
        __builtin_amdgcn_s_setprio(0);
        smax(qw0 - k0, S0, pa0, lsum[0]);

        bf16x8 ef1[5][2];
        eread(16 * w + 64 - k0, ef1);
        ps_write(S0);

        f32x4 S1[4], pa1[5];
        __builtin_amdgcn_s_setprio(1);
        qkmfma(qf[1], kf, S1);
        pamfma(qf[1], ef1, pa1);
        pvmfma(vf, O[0]);
        __builtin_amdgcn_s_setprio(0);

        smax(qw1 - k0, S1, pa1, lsum[1]);
        ps_write(S1);
        __builtin_amdgcn_s_setprio(1);
        pvmfma(vf, O[1]);
        __builtin_amdgcn_s_setprio(0);
    }

    // ---- peeled diagonal tile (c0 fully masked, skip it) ----
    if (haspeel) {
        const int kt = kt1 - 1, k0 = kt * 64;
        __syncthreads();
        bf16x8 kf[4][2], vf[4][2];
        load_kv((const char*)Ks[kt & 1], (const char*)Vts[kt & 1], kf, vf);
        bf16x8 ef1[5][2];
        eread(16 * w + 64 - k0, ef1);
        f32x4 S1[4], pa1[5];
        qkmfma(qf[1], kf, S1);
        pamfma(qf[1], ef1, pa1);
        smax(qw1 - k0, S1, pa1, lsum[1]);
        ps_write(S1);
        pvmfma(vf, O[1]);
    }

    if (!split) {
#pragma unroll
        for (int c = 0; c < 2; ++c) {
#pragma unroll
            for (int rg = 0; rg < 4; ++rg) {
                float s = lsum[c][rg];
                s += __shfl_xor(s, 1);
                s += __shfl_xor(s, 2);
                s += __shfl_xor(s, 4);
                s += __shfl_xor(s, 8);
                float inv = 1.0f / s;
                int q = (c ? qw1 : qw0) + quad * 4 + rg;
                size_t ro = ((size_t)(b * SEQ + q)) * NH + n * 64;
                o[ro +  0 + l16] = (bf16)(O[c][0][rg] * inv);
                o[ro + 16 + l16] = (bf16)(O[c][1][rg] * inv);
                o[ro + 32 + l16] = (bf16)(O[c][2][rg] * inv);
                o[ro + 48 + l16] = (bf16)(O[c][3][rg] * inv);
            }
        }
    } else {
        // partial write: unnormalized f32 O + row lsum (q rows are >= 1024)
        const int pslot = pr;  // 0 or 1
        float* Ob = Opart + ((size_t)(pslot * 32 + bx)) * 1024 * 64;
        float* Lb = Lpart + ((size_t)(pslot * 32 + bx)) * 1024;
#pragma unroll
        for (int c = 0; c < 2; ++c) {
#pragma unroll
            for (int rg = 0; rg < 4; ++rg) {
                float s = lsum[c][rg];
                s += __shfl_xor(s, 1);
                s += __shfl_xor(s, 2);
                s += __shfl_xor(s, 4);
                s += __shfl_xor(s, 8);
                int q = (c ? qw1 : qw0) + quad * 4 + rg;
                int rloc = q - 1024;
                size_t ro = (size_t)rloc * 64;
                Ob[ro +  0 + l16] = O[c][0][rg];
                Ob[ro + 16 + l16] = O[c][1][rg];
                Ob[ro + 32 + l16] = O[c][2][rg];
                Ob[ro + 48 + l16] = O[c][3][rg];
                if (l16 == 0) Lb[rloc] = s;
            }
        }
    }
}

// ---------------------------------------------------------------------------
// Merge the two split-K partials and normalize -> bf16 o rows [1024, 2048).
// 2048 blocks x 256 threads, one float4 (4 head-elems) per thread.
// ---------------------------------------------------------------------------
__global__ __launch_bounds__(256) void merge_kernel(
    const float* __restrict__ Opart, const float* __restrict__ Lpart,
    bf16* __restrict__ o)
{
    int idx = blockIdx.x * 256 + threadIdx.x;   // 524288 total
    int h4 = idx & 15;
    int r  = (idx >> 4) & 1023;
    int bx = idx >> 14;
    size_t i0 = (((size_t)bx        * 1024 + r) * 64 + h4 * 4);
    size_t i1 = (((size_t)(32 + bx) * 1024 + r) * 64 + h4 * 4);
    float4 a = *(const float4*)(Opart + i0);
    float4 c = *(const float4*)(Opart + i1);
    float inv = 1.0f / (Lpart[bx * 1024 + r] + Lpart[32 * 1024 + bx * 1024 + r]);
    int b = bx >> 4, n = bx & 15;
    size_t ro = ((size_t)(b * SEQ + 1024 + r)) * NH + n * 64 + h4 * 4;
    ushort4 wv;
    wv.x = bf16_bits((a.x + c.x) * inv);
    wv.y = bf16_bits((a.y + c.y) * inv);
    wv.z = bf16_bits((a.z + c.z) * inv);
    wv.w = bf16_bits((a.w + c.w) * inv);
    *(ushort4*)(o + ro) = wv;
}

// ---------------------------------------------------------------------------
extern "C" void kernel_launch(void* const* d_in, const int* in_sizes, int n_in,
                              void* d_out, int out_size, void* d_ws, size_t ws_size,
                              hipStream_t stream) {
    const float* inp        = (const float*)d_in[0];
    const float* qkv_w      = (const float*)d_in[1];
    const float* q_bias     = (const float*)d_in[2];
    const float* positional = (const float*)d_in[3];
    const float* out_kernel = (const float*)d_in[4];
    const float* out_bias   = (const float*)d_in[5];

    char* p = (char*)d_ws;
    auto alloc = [&](size_t bytes) {
        char* q = p; p += (bytes + 255) & ~(size_t)255; return q;
    };
    // NOTE: vtbuf -> embT -> sins_bf adjacency is load-slack-critical.
    // a_bf, wt_qkv, opext are contiguous; Opart (f32 partials, 16.78 MB)
    // aliases them (both are dead once mfma_gemm<1> completes, before attn).
    // Lpart aliases wt_pos (dead after gemm<1>).
    bf16* qbuf    = (bf16*)alloc((size_t)BATCH * HEADS * SEQ * HSIZE * 2);
    bf16* kbuf    = (bf16*)alloc((size_t)BATCH * HEADS * SEQ * HSIZE * 2);
    bf16* vtbuf   = (bf16*)alloc((size_t)BATCH * HEADS * SEQ * HSIZE * 2);
    bf16* embT    = (bf16*)alloc((size_t)HEADS * SEQ * HSIZE * 2);  // negative-d slack before
    bf16* sins_bf = (bf16*)alloc((size_t)SEQ * FREQS * 2);          // d>=2048 slack after embT
    bf16* obuf    = (bf16*)alloc((size_t)BATCH * SEQ * NH * 2);
    bf16* wt_out  = (bf16*)alloc((size_t)NH * DMODEL * 2);
    bf16* wt_pos  = (bf16*)alloc((size_t)NH * FREQS * 2);
    bf16* a_bf    = (bf16*)alloc((size_t)BATCH * SEQ * DMODEL * 2);   // 8,388,608 B
    bf16* wt_qkv  = (bf16*)alloc((size_t)QKVN * DMODEL * 2);          // 6,291,456 B
    (void)       alloc((size_t)2097152);                              // Opart tail
    float* Opart  = (float*)a_bf;    // 2 x 32 x 1024 x 64 f32 = 16,777,216 B
    float* Lpart  = (float*)wt_pos;  // 2 x 32 x 1024 f32 = 262,144 B

    const float qkv_scale = (float)pow(3.0 * DMODEL * HSIZE * HEADS, -0.25);
    const float emb_scale = 0.0625f;   // 256^-0.5
    const float out_scale = 0.03125f;  // (1024*1024)^-0.25

    // 1. merged prep (cast + sins + 3 transposes)
    prep_kernel<<<10496, 256, 0, stream>>>(
        inp, qkv_w, out_kernel, positional, a_bf, wt_qkv, wt_out, wt_pos, sins_bf);

    // 2. merged QKV projection + emb GEMM
    mfma_gemm<1><<<dim3(32, 32), 256, 0, stream>>>(
        a_bf, wt_qkv, DMODEL, qkv_scale, q_bias, nullptr, qbuf, kbuf, vtbuf,
        sins_bf, wt_pos, embT, emb_scale);

    // 3. flash attention (split-K balanced) -> bf16 o rows <1024, partials >=1024
    attn_kernel<<<dim3(32, 24), 256, 0, stream>>>(
        qbuf, kbuf, vtbuf, embT, obuf, Opart, Lpart);

    // 3b. merge split-K partials for rows >= 1024
    merge_kernel<<<2048, 256, 0, stream>>>(Opart, Lpart, obuf);

    // 4. output projection (fp32 out)
    mfma_gemm<0><<<dim3(8, 32), 256, 0, stream>>>(
        obuf, wt_out, DMODEL, out_scale, out_bias, (float*)d_out,
        nullptr, nullptr, nullptr, nullptr, nullptr, nullptr, 0.0f);
}

// Round 4
// 243.563 us; speedup vs baseline: 1.0822x; 1.0637x over previous
//
#include <hip/hip_runtime.h>
#include <math.h>

#define BATCH 2
#define SEQ 2048
#define DMODEL 1024
#define HEADS 16
#define HSIZE 64
#define FREQS 256
#define NH 1024
#define QKVN 3072

typedef __bf16 bf16;
typedef __bf16 bf16x8 __attribute__((ext_vector_type(8)));
typedef float f32x4 __attribute__((ext_vector_type(4)));

static __device__ __forceinline__ unsigned short bf16_bits(float v) {
    bf16 b = (bf16)v; return __builtin_bit_cast(unsigned short, b);
}

// async global->LDS, 16 bytes per lane; LDS dest = wave-uniform base + lane*16
static __device__ __forceinline__ void gload16(const void* g, void* l) {
    __builtin_amdgcn_global_load_lds(
        (const __attribute__((address_space(1))) unsigned int*)g,
        (__attribute__((address_space(3))) unsigned int*)l, 16, 0, 0);
}

// ---------------------------------------------------------------------------
// Merged prep: fp32->bf16 cast of input, fp64 sinusoid table, and the three
// weight transpose+casts, decoded from a 1D block range. One launch.
// ---------------------------------------------------------------------------
__global__ __launch_bounds__(256) void prep_kernel(
    const float* __restrict__ inp, const float* __restrict__ qkv_w,
    const float* __restrict__ out_kernel, const float* __restrict__ positional,
    bf16* __restrict__ a_bf, bf16* __restrict__ wt_qkv,
    bf16* __restrict__ wt_out, bf16* __restrict__ wt_pos,
    bf16* __restrict__ sins_bf)
{
    __shared__ float tile[32][33];
    const int id = blockIdx.x, t = threadIdx.x;

    if (id < 4096) {            // input cast
        int i = id * 256 + t;
        float4 v = ((const float4*)inp)[i];
        ushort4 o;
        o.x = bf16_bits(v.x); o.y = bf16_bits(v.y);
        o.z = bf16_bits(v.z); o.w = bf16_bits(v.w);
        ((ushort4*)a_bf)[i] = o;
        return;
    }
    if (id < 6144) {            // sinusoid table (fp64, matches numpy)
        int i = (id - 4096) * 256 + t;
        int s = i >> 8, f = i & 255;
        double e = -(double)((f >> 1) << 1) / (double)FREQS;
        double invf = pow(10000.0, e);
        double ang = (double)s * invf;
        double v = (f & 1) ? cos(ang) : sin(ang);
        sins_bf[i] = (bf16)(float)(1.4142135623730951 * v);
        return;
    }
    int id2 = id - 6144;
    const float* src; bf16* dst; int R, C, c0, r0;
    if (id2 < 3072) {
        src = qkv_w; dst = wt_qkv; R = 1024; C = 3072;
        c0 = (id2 % 96) * 32; r0 = (id2 / 96) * 32;
    } else if (id2 < 4096) {
        id2 -= 3072;
        src = out_kernel; dst = wt_out; R = 1024; C = 1024;
        c0 = (id2 & 31) * 32; r0 = (id2 >> 5) * 32;
    } else {
        id2 -= 4096;
        src = positional; dst = wt_pos; R = 256; C = 1024;
        c0 = (id2 & 31) * 32; r0 = (id2 >> 5) * 32;
    }
    const int tx = t & 31, ty = t >> 5;
#pragma unroll
    for (int i = 0; i < 4; i++)
        tile[ty + i * 8][tx] = src[(size_t)(r0 + ty + i * 8) * C + c0 + tx];
    __syncthreads();
#pragma unroll
    for (int i = 0; i < 4; i++)
        dst[(size_t)(c0 + ty + i * 8) * R + r0 + tx] = (bf16)tile[tx][ty + i * 8];
}

// ---------------------------------------------------------------------------
// Pipelined bf16 MFMA GEMM v2: 128x128 tile, BK=32, THREE LDS buffers,
// 2-deep prefetch, raw s_barrier + counted s_waitcnt vmcnt(4) -- loads for
// tile kk+1 stay in flight across the barrier (T3/T4); only tile kk's 4
// loads are drained. No ds_writes in the loop, so the relaxed barrier is
// safe: ds_read consumers are compiler-waited (lgkmcnt), and the DMA
// LDS-writes of tile kk are ordered by each wave's own vmcnt wait + barrier.
// ---------------------------------------------------------------------------
template<int EPI>
__global__ __launch_bounds__(256) void mfma_gemm(
    const bf16* __restrict__ A, const bf16* __restrict__ Bt,
    int K, float alpha, const float* __restrict__ bias,
    float* __restrict__ outf, bf16* __restrict__ ob0, bf16* __restrict__ ob1,
    bf16* __restrict__ ob2,
    const bf16* __restrict__ A2, const bf16* __restrict__ Bt2,
    bf16* __restrict__ ob3, float alpha2)
{
    __shared__ __align__(16) bf16 Atile[3][128 * 32];
    __shared__ __align__(16) bf16 Btile[3][128 * 32];

    const int t    = threadIdx.x;
    const int lane = t & 63;
    const int w    = t >> 6;
    const int quad = lane >> 4;
    const int l16  = lane & 15;
    const int wm   = (w >> 1) * 64;
    const int wn   = (w & 1) * 64;

    bool embp = false;
    int m0 = blockIdx.y * 128, n0 = blockIdx.x * 128, Kl = K;
    const bf16* Ap = A; const bf16* Btp = Bt; float al = alpha;
    if constexpr (EPI == 1) {
        if (blockIdx.x >= 24) {
            if (blockIdx.y >= 16) return;   // emb has only 2048 rows
            embp = true;
            n0 = (blockIdx.x - 24) * 128;
            Kl = FREQS; Ap = A2; Btp = Bt2; al = alpha2;
        }
    }
    const bool swapv = (EPI == 1) && !embp && (n0 >= 2048);

    // staging coords (16B chunk swizzle)
    const int rS = t >> 2;
    const int cS = (t & 3) ^ ((rS >> 1) & 3);
    const bf16* ag0 = Ap  + (size_t)(m0 + rS) * Kl + cS * 8;
    const bf16* ag1 = ag0 + (size_t)64 * Kl;
    const bf16* bg0 = Btp + (size_t)(n0 + rS) * Kl + cS * 8;
    const bf16* bg1 = bg0 + (size_t)64 * Kl;

    // stage tile ks into buffer ks%3 (4 gload16 per thread = 4 vmcnt events)
    auto stage = [&](int ks) {
        char* ad = (char*)Atile[ks % 3];
        char* bd = (char*)Btile[ks % 3];
        const int ko = ks * 32;
        gload16(ag0 + ko, ad + t * 16);
        gload16(ag1 + ko, ad + 4096 + t * 16);
        gload16(bg0 + ko, bd + t * 16);
        gload16(bg1 + ko, bd + 4096 + t * 16);
    };

    // fragment LDS offsets (within one buffer)
    int aoff[4], boff[4];
#pragma unroll
    for (int mi = 0; mi < 4; ++mi) {
        int r = wm + mi * 16 + l16;
        aoff[mi] = r * 32 + ((quad ^ ((r >> 1) & 3)) * 8);
    }
#pragma unroll
    for (int ni = 0; ni < 4; ++ni) {
        int r = wn + ni * 16 + l16;
        boff[ni] = r * 32 + ((quad ^ ((r >> 1) & 3)) * 8);
    }

    const int nK = Kl >> 5;          // >= 8 for all dispatches here
    stage(0);
    stage(1);

    f32x4 acc[4][4] = {};

    for (int kk = 0; kk < nK; ++kk) {
        // wait for tile kk's 4 loads; leave tile kk+1's 4 in flight
        if (kk + 1 < nK) asm volatile("s_waitcnt vmcnt(4)" ::: "memory");
        else             asm volatile("s_waitcnt vmcnt(0)" ::: "memory");
        __builtin_amdgcn_s_barrier();
        __builtin_amdgcn_sched_barrier(0);

        const bf16* ab = Atile[kk % 3];
        const bf16* bb = Btile[kk % 3];
        bf16x8 af[4], bfr[4];
#pragma unroll
        for (int mi = 0; mi < 4; ++mi) af[mi] = *(const bf16x8*)(ab + aoff[mi]);
#pragma unroll
        for (int ni = 0; ni < 4; ++ni) bfr[ni] = *(const bf16x8*)(bb + boff[ni]);

        if (kk + 2 < nK) stage(kk + 2);   // 2-deep prefetch

        if (!swapv) {
#pragma unroll
            for (int mi = 0; mi < 4; ++mi)
#pragma unroll
                for (int ni = 0; ni < 4; ++ni)
                    acc[mi][ni] = __builtin_amdgcn_mfma_f32_16x16x32_bf16(
                        af[mi], bfr[ni], acc[mi][ni], 0, 0, 0);
        } else {
#pragma unroll
            for (int mi = 0; mi < 4; ++mi)
#pragma unroll
                for (int ni = 0; ni < 4; ++ni)
                    acc[mi][ni] = __builtin_amdgcn_mfma_f32_16x16x32_bf16(
                        bfr[ni], af[mi], acc[mi][ni], 0, 0, 0);
        }
    }

    if constexpr (EPI == 0) {
#pragma unroll
        for (int mi = 0; mi < 4; ++mi)
#pragma unroll
            for (int ni = 0; ni < 4; ++ni) {
                int col = n0 + wn + ni * 16 + l16;
                float bb = bias[col];
#pragma unroll
                for (int rg = 0; rg < 4; ++rg) {
                    int row = m0 + wm + mi * 16 + quad * 4 + rg;
                    outf[(size_t)row * NH + col] = acc[mi][ni][rg] * al + bb;
                }
            }
    } else {
        if (embp) {  // embT[head][d][h'] chunk-swizzled by (d+63)&7
#pragma unroll
            for (int mi = 0; mi < 4; ++mi)
#pragma unroll
                for (int ni = 0; ni < 4; ++ni) {
                    int col = n0 + wn + ni * 16 + l16;
                    int head = col >> 6, h = col & 63;
#pragma unroll
                    for (int rg = 0; rg < 4; ++rg) {
                        int d = m0 + wm + mi * 16 + quad * 4 + rg;
                        int hs = h ^ (((d + 63) & 7) << 3);
                        ob3[((size_t)(head * SEQ + d)) * 64 + hs] =
                            (bf16)(acc[mi][ni][rg] * al);
                    }
                }
        } else if (n0 >= 2048) {
            // swapped: acc rows = head-cols, cols = seq-rows -> Vt swizzled
#pragma unroll
            for (int mi = 0; mi < 4; ++mi)
#pragma unroll
                for (int ni = 0; ni < 4; ++ni) {
                    int mcol = m0 + wm + mi * 16 + l16;
                    int bb = mcol >> 11, s = mcol & 2047;
#pragma unroll
                    for (int rg = 0; rg < 4; ++rg) {
                        int hg = n0 + wn + ni * 16 + quad * 4 + rg;
                        int head = (hg & 1023) >> 6, h = hg & 63;
                        int ss = s ^ ((h & 7) << 3);
                        ob2[((size_t)((bb * 16 + head) * 64 + h)) * SEQ + ss] =
                            (bf16)(acc[mi][ni][rg] * al);
                    }
                }
        } else {
            const int whichk = (n0 >= 1024);
#pragma unroll
            for (int mi = 0; mi < 4; ++mi)
#pragma unroll
                for (int ni = 0; ni < 4; ++ni) {
                    int cg   = (n0 + wn + ni * 16 + l16) & 1023;
                    int head = cg >> 6, h = cg & 63;
                    float qbv = whichk ? 0.0f : bias[cg];
#pragma unroll
                    for (int rg = 0; rg < 4; ++rg) {
                        int row = m0 + wm + mi * 16 + quad * 4 + rg;
                        int bb = row >> 11, s = row & 2047;
                        float v = acc[mi][ni][rg] * al;
                        if (whichk) {
                            int hs = h ^ ((s & 7) << 3);
                            ob1[((size_t)((bb * 16 + head) * SEQ + s)) * 64 + hs] = (bf16)v;
                        } else {
                            ob0[((size_t)((bb * 16 + head) * SEQ + s)) * 64 + h] =
                                (bf16)((v + qbv) * 0.125f);
                        }
                    }
                }
        }
    }
}

// ---------------------------------------------------------------------------
// MFMA flash attention v7 (unchanged from round 3): split-K load balancing,
// no-max softmax -> additive merge.
// ---------------------------------------------------------------------------
__device__ const unsigned char YQC[24]  = {15,15,7,14,14,13,13,6,12,12,11,11,
                                           5,10,10,9,9,4,8,8,3,2,1,0};
__device__ const unsigned char YPRT[24] = {0,1,2,0,1,0,1,2,0,1,0,1,
                                           2,0,1,0,1,2,0,1,2,2,2,2}; // 2=full

__global__ __launch_bounds__(256, 2) void attn_kernel(
    const bf16* __restrict__ Qb, const bf16* __restrict__ Kb,
    const bf16* __restrict__ Vtb, const bf16* __restrict__ Eb,
    bf16* __restrict__ o, float* __restrict__ Opart, float* __restrict__ Lpart)
{
    __shared__ __align__(16) bf16 Ks[2][4096];
    __shared__ __align__(16) bf16 Vts[2][4096];
    __shared__ __align__(16) bf16 Es[256 * 64];
    __shared__ __align__(16) bf16 PS[4][16][72];

    const int t    = threadIdx.x;
    const int lane = t & 63;
    const int w    = t >> 6;
    const int quad = lane >> 4;
    const int l16  = lane & 15;

    const int bx = blockIdx.x;
    const int b  = bx >> 4, n = bx & 15;
    const int yy = blockIdx.y;
    const int qc = YQC[yy];
    const int pr = YPRT[yy];
    const int q0 = qc * 128;
    const int KT = 2 * qc + 2;
    const int kt0 = (pr == 1) ? (qc + 1) : 0;
    const int kt1 = (pr == 0) ? (qc + 1) : KT;   // exclusive end of MY tiles
    const bool haspeel = (pr != 0);              // my range contains the diagonal tile
    const bool split   = (pr != 2);
    const int qw0 = q0 + 16 * w;
    const int qw1 = qw0 + 64;

    const bf16* __restrict__ Qp = Qb  + (size_t)bx * SEQ * 64;
    const bf16* __restrict__ Kp = Kb  + (size_t)bx * SEQ * 64;
    const bf16* __restrict__ Vp = Vtb + (size_t)bx * SEQ * 64;
    const bf16* __restrict__ Ep = Eb  + (size_t)n  * SEQ * 64;

    const int key8 = (l16 & 7) << 3;
    const int ec0  = ((quad * 8) ^ key8) * 2;
    const int ec1  = ((32 + quad * 8) ^ key8) * 2;

    bf16x8 qf[2][2];
    qf[0][0] = *(const bf16x8*)(Qp + (size_t)(qw0 + l16) * 64 + quad * 8);
    qf[0][1] = *(const bf16x8*)(Qp + (size_t)(qw0 + l16) * 64 + 32 + quad * 8);
    qf[1][0] = *(const bf16x8*)(Qp + (size_t)(qw1 + l16) * 64 + quad * 8);
    qf[1][1] = *(const bf16x8*)(Qp + (size_t)(qw1 + l16) * 64 + 32 + quad * 8);

    int dsta[4];
    bool condp[4];
#pragma unroll
    for (int rg = 0; rg < 4; ++rg) {
        int rr   = quad * 4 + rg;
        int l16c = (rr + 15 - l16) & 15;
        dsta[rg]  = ((lane & 48) + l16c) << 2;
        condp[rg] = rr > l16c;
    }

    f32x4 O[2][4] = {};
    float lsum[2][4] = {};

    {   // prologue: stage tile kt0 + the 192-row E window at ring phase rI0
        const bf16* ksrc = Kp + kt0 * 4096;
        char* kd = (char*)Ks[kt0 & 1];
        char* vd = (char*)Vts[kt0 & 1];
        gload16(ksrc + t * 8,        kd + t * 16);
        gload16(ksrc + 2048 + t * 8, kd + 4096 + t * 16);
        gload16(Vp + (size_t)(t >> 3) * SEQ + kt0 * 64 + (t & 7) * 8,        vd + t * 16);
        gload16(Vp + (size_t)((t >> 3) + 32) * SEQ + kt0 * 64 + (t & 7) * 8, vd + 4096 + t * 16);
        const long D0 = (long)q0 - 64 * kt0 - 63;
        const int rI0 = (-64 * kt0) & 255;
#pragma unroll
        for (int g = 0; g < 6; ++g) {
            const int sI = (rI0 + 32 * g) & 255;
            gload16(Ep + (D0 + 32 * g) * 64 + t * 8, (char*)Es + sI * 128 + t * 16);
        }
    }

    // ---- phase helpers ----
    auto load_kv = [&](const char* kb, const char* vb,
                       bf16x8 (&kf)[4][2], bf16x8 (&vf)[4][2]) {
#pragma unroll
        for (int j = 0; j < 4; ++j) {
            const char* kp = kb + (j * 16 + l16) * 128;
            kf[j][0] = *(const bf16x8*)(kp + ec0);
            kf[j][1] = *(const bf16x8*)(kp + ec1);
            const char* vp = vb + (j * 16 + l16) * 128;
            vf[j][0] = *(const bf16x8*)(vp + ec0);
            vf[j][1] = *(const bf16x8*)(vp + ec1);
        }
    };
    auto eread = [&](int rb, bf16x8 (&ef)[5][2]) {
#pragma unroll
        for (int jj = 0; jj < 5; ++jj) {
            const char* ep = (const char*)Es + ((rb + 16 * jj + l16) & 255) * 128;
            ef[jj][0] = *(const bf16x8*)(ep + ec0);
            ef[jj][1] = *(const bf16x8*)(ep + ec1);
        }
    };
    auto qkmfma = [&](const bf16x8 (&q2)[2], const bf16x8 (&kf)[4][2],
                      f32x4 (&S)[4]) {
#pragma unroll
        for (int j = 0; j < 4; ++j) {
            f32x4 a = {0, 0, 0, 0};
            a = __builtin_amdgcn_mfma_f32_16x16x32_bf16(q2[1], kf[j][1], a, 0, 0, 0);
            a = __builtin_amdgcn_mfma_f32_16x16x32_bf16(q2[0], kf[j][0], a, 0, 0, 0);
            S[j] = a;
        }
    };
    auto pamfma = [&](const bf16x8 (&q2)[2], const bf16x8 (&ef)[5][2],
                      f32x4 (&pa)[5]) {
#pragma unroll
        for (int jj = 0; jj < 5; ++jj) {
            f32x4 a = {0, 0, 0, 0};
            a = __builtin_amdgcn_mfma_f32_16x16x32_bf16(q2[1], ef[jj][1], a, 0, 0, 0);
            a = __builtin_amdgcn_mfma_f32_16x16x32_bf16(q2[0], ef[jj][0], a, 0, 0, 0);
            pa[jj] = a;
        }
    };
    auto smax = [&](int kq, f32x4 (&S)[4], const f32x4 (&pa)[5], float (&ls)[4]) {
#pragma unroll
        for (int j = 0; j < 4; ++j) {
#pragma unroll
            for (int rg = 0; rg < 4; ++rg) {
                float vsel = condp[rg] ? pa[4 - j][rg] : pa[3 - j][rg];
                int pv = __builtin_amdgcn_ds_permute(dsta[rg], __float_as_int(vsel));
                float sv = S[j][rg] + __int_as_float(pv);
                bool valid = (j * 16 + l16) <= (kq + quad * 4 + rg);
                S[j][rg] = valid ? __expf(sv) : 0.0f;
            }
        }
#pragma unroll
        for (int rg = 0; rg < 4; ++rg)
            ls[rg] += S[0][rg] + S[1][rg] + S[2][rg] + S[3][rg];
    };
    auto ps_write = [&](const f32x4 (&S)[4]) {
#pragma unroll
        for (int j = 0; j < 4; ++j)
#pragma unroll
            for (int rg = 0; rg < 4; ++rg)
                PS[w][quad * 4 + rg][j * 16 + l16] = (bf16)S[j][rg];
    };
    auto pvmfma = [&](const bf16x8 (&vf)[4][2], f32x4 (&Oc)[4]) {
        bf16x8 pf0 = *(const bf16x8*)(&PS[w][l16][quad * 8]);
        bf16x8 pf1 = *(const bf16x8*)(&PS[w][l16][32 + quad * 8]);
#pragma unroll
        for (int j4 = 0; j4 < 4; ++j4) {
            Oc[j4] = __builtin_amdgcn_mfma_f32_16x16x32_bf16(pf1, vf[j4][1], Oc[j4], 0, 0, 0);
            Oc[j4] = __builtin_amdgcn_mfma_f32_16x16x32_bf16(pf0, vf[j4][0], Oc[j4], 0, 0, 0);
        }
    };

    // ---- steady state over my tile range (minus peel if diagonal is mine) ----
    const int ktE = kt1 - (haspeel ? 1 : 0);
    for (int kt = kt0; kt < ktE; ++kt) {
        const int k0 = kt * 64;
        __syncthreads();

        const int nt = kt + 1;
        if (nt < kt1) {   // prefetch next tile of MY range
            bf16* kd = Ks[nt & 1];
            bf16* vd = Vts[nt & 1];
            const bf16* ksrc = Kp + nt * 4096;
            gload16(ksrc + t * 8,        (char*)kd + t * 16);
            gload16(ksrc + 2048 + t * 8, (char*)kd + 4096 + t * 16);
            gload16(Vp + (size_t)(t >> 3) * SEQ + nt * 64 + (t & 7) * 8,
                    (char*)vd + t * 16);
            gload16(Vp + (size_t)((t >> 3) + 32) * SEQ + nt * 64 + (t & 7) * 8,
                    (char*)vd + 4096 + t * 16);
            const long d0 = (long)q0 - nt * 64 - 63;
            const int rI = (-64 * nt) & 255;
            gload16(Ep + d0 * 64 + t * 8,        (char*)Es + rI * 128 + t * 16);
            gload16(Ep + (d0 + 32) * 64 + t * 8, (char*)Es + rI * 128 + 4096 + t * 16);
        }

        bf16x8 kf[4][2], vf[4][2];
        load_kv((const char*)Ks[kt & 1], (const char*)Vts[kt & 1], kf, vf);

        // c0: scores
        bf16x8 ef0[5][2];
        eread(16 * w - k0, ef0);
        f32x4 S0[4], pa0[5];
        __builtin_amdgcn_s_setprio(1);
        qkmfma(qf[0], kf, S0);
        pamfma(qf[0], ef0, pa0);
        __builtin_amdgcn_s_setprio(0);
        smax(qw0 - k0, S0, pa0, lsum[0]);

        bf16x8 ef1[5][2];
        eread(16 * w + 64 - k0, ef1);
        ps_write(S0);

        f32x4 S1[4], pa1[5];
        __builtin_amdgcn_s_setprio(1);
        qkmfma(qf[1], kf, S1);
        pamfma(qf[1], ef1, pa1);
        pvmfma(vf, O[0]);
        __builtin_amdgcn_s_setprio(0);

        smax(qw1 - k0, S1, pa1, lsum[1]);
        ps_write(S1);
        __builtin_amdgcn_s_setprio(1);
        pvmfma(vf, O[1]);
        __builtin_amdgcn_s_setprio(0);
    }

    // ---- peeled diagonal tile (c0 fully masked, skip it) ----
    if (haspeel) {
        const int kt = kt1 - 1, k0 = kt * 64;
        __syncthreads();
        bf16x8 kf[4][2], vf[4][2];
        load_kv((const char*)Ks[kt & 1], (const char*)Vts[kt & 1], kf, vf);
        bf16x8 ef1[5][2];
        eread(16 * w + 64 - k0, ef1);
        f32x4 S1[4], pa1[5];
        qkmfma(qf[1], kf, S1);
        pamfma(qf[1], ef1, pa1);
        smax(qw1 - k0, S1, pa1, lsum[1]);
        ps_write(S1);
        pvmfma(vf, O[1]);
    }

    if (!split) {
#pragma unroll
        for (int c = 0; c < 2; ++c) {
#pragma unroll
            for (int rg = 0; rg < 4; ++rg) {
                float s = lsum[c][rg];
                s += __shfl_xor(s, 1);
                s += __shfl_xor(s, 2);
                s += __shfl_xor(s, 4);
                s += __shfl_xor(s, 8);
                float inv = 1.0f / s;
                int q = (c ? qw1 : qw0) + quad * 4 + rg;
                size_t ro = ((size_t)(b * SEQ + q)) * NH + n * 64;
                o[ro +  0 + l16] = (bf16)(O[c][0][rg] * inv);
                o[ro + 16 + l16] = (bf16)(O[c][1][rg] * inv);
                o[ro + 32 + l16] = (bf16)(O[c][2][rg] * inv);
                o[ro + 48 + l16] = (bf16)(O[c][3][rg] * inv);
            }
        }
    } else {
        // partial write: unnormalized f32 O + row lsum (q rows are >= 1024)
        const int pslot = pr;  // 0 or 1
        float* Ob = Opart + ((size_t)(pslot * 32 + bx)) * 1024 * 64;
        float* Lb = Lpart + ((size_t)(pslot * 32 + bx)) * 1024;
#pragma unroll
        for (int c = 0; c < 2; ++c) {
#pragma unroll
            for (int rg = 0; rg < 4; ++rg) {
                float s = lsum[c][rg];
                s += __shfl_xor(s, 1);
                s += __shfl_xor(s, 2);
                s += __shfl_xor(s, 4);
                s += __shfl_xor(s, 8);
                int q = (c ? qw1 : qw0) + quad * 4 + rg;
                int rloc = q - 1024;
                size_t ro = (size_t)rloc * 64;
                Ob[ro +  0 + l16] = O[c][0][rg];
                Ob[ro + 16 + l16] = O[c][1][rg];
                Ob[ro + 32 + l16] = O[c][2][rg];
                Ob[ro + 48 + l16] = O[c][3][rg];
                if (l16 == 0) Lb[rloc] = s;
            }
        }
    }
}

// ---------------------------------------------------------------------------
// Merge the two split-K partials and normalize -> bf16 o rows [1024, 2048).
// ---------------------------------------------------------------------------
__global__ __launch_bounds__(256) void merge_kernel(
    const float* __restrict__ Opart, const float* __restrict__ Lpart,
    bf16* __restrict__ o)
{
    int idx = blockIdx.x * 256 + threadIdx.x;   // 524288 total
    int h4 = idx & 15;
    int r  = (idx >> 4) & 1023;
    int bx = idx >> 14;
    size_t i0 = (((size_t)bx        * 1024 + r) * 64 + h4 * 4);
    size_t i1 = (((size_t)(32 + bx) * 1024 + r) * 64 + h4 * 4);
    float4 a = *(const float4*)(Opart + i0);
    float4 c = *(const float4*)(Opart + i1);
    float inv = 1.0f / (Lpart[bx * 1024 + r] + Lpart[32 * 1024 + bx * 1024 + r]);
    int b = bx >> 4, n = bx & 15;
    size_t ro = ((size_t)(b * SEQ + 1024 + r)) * NH + n * 64 + h4 * 4;
    ushort4 wv;
    wv.x = bf16_bits((a.x + c.x) * inv);
    wv.y = bf16_bits((a.y + c.y) * inv);
    wv.z = bf16_bits((a.z + c.z) * inv);
    wv.w = bf16_bits((a.w + c.w) * inv);
    *(ushort4*)(o + ro) = wv;
}

// ---------------------------------------------------------------------------
extern "C" void kernel_launch(void* const* d_in, const int* in_sizes, int n_in,
                              void* d_out, int out_size, void* d_ws, size_t ws_size,
                              hipStream_t stream) {
    const float* inp        = (const float*)d_in[0];
    const float* qkv_w      = (const float*)d_in[1];
    const float* q_bias     = (const float*)d_in[2];
    const float* positional = (const float*)d_in[3];
    const float* out_kernel = (const float*)d_in[4];
    const float* out_bias   = (const float*)d_in[5];

    char* p = (char*)d_ws;
    auto alloc = [&](size_t bytes) {
        char* q = p; p += (bytes + 255) & ~(size_t)255; return q;
    };
    // NOTE: vtbuf -> embT -> sins_bf adjacency is load-slack-critical.
    // Opart (f32 partials) aliases a_bf+wt_qkv (dead after mfma_gemm<1>);
    // Lpart aliases wt_pos (dead after gemm<1>).
    bf16* qbuf    = (bf16*)alloc((size_t)BATCH * HEADS * SEQ * HSIZE * 2);
    bf16* kbuf    = (bf16*)alloc((size_t)BATCH * HEADS * SEQ * HSIZE * 2);
    bf16* vtbuf   = (bf16*)alloc((size_t)BATCH * HEADS * SEQ * HSIZE * 2);
    bf16* embT    = (bf16*)alloc((size_t)HEADS * SEQ * HSIZE * 2);  // negative-d slack before
    bf16* sins_bf = (bf16*)alloc((size_t)SEQ * FREQS * 2);          // d>=2048 slack after embT
    bf16* obuf    = (bf16*)alloc((size_t)BATCH * SEQ * NH * 2);
    bf16* wt_out  = (bf16*)alloc((size_t)NH * DMODEL * 2);
    bf16* wt_pos  = (bf16*)alloc((size_t)NH * FREQS * 2);
    bf16* a_bf    = (bf16*)alloc((size_t)BATCH * SEQ * DMODEL * 2);   // 8,388,608 B
    bf16* wt_qkv  = (bf16*)alloc((size_t)QKVN * DMODEL * 2);          // 6,291,456 B
    (void)       alloc((size_t)2097152);                              // Opart tail
    float* Opart  = (float*)a_bf;    // 2 x 32 x 1024 x 64 f32 = 16,777,216 B
    float* Lpart  = (float*)wt_pos;  // 2 x 32 x 1024 f32 = 262,144 B

    const float qkv_scale = (float)pow(3.0 * DMODEL * HSIZE * HEADS, -0.25);
    const float emb_scale = 0.0625f;   // 256^-0.5
    const float out_scale = 0.03125f;  // (1024*1024)^-0.25

    // 1. merged prep (cast + sins + 3 transposes)
    prep_kernel<<<10496, 256, 0, stream>>>(
        inp, qkv_w, out_kernel, positional, a_bf, wt_qkv, wt_out, wt_pos, sins_bf);

    // 2. merged QKV projection + emb GEMM
    mfma_gemm<1><<<dim3(32, 32), 256, 0, stream>>>(
        a_bf, wt_qkv, DMODEL, qkv_scale, q_bias, nullptr, qbuf, kbuf, vtbuf,
        sins_bf, wt_pos, embT, emb_scale);

    // 3. flash attention (split-K balanced) -> bf16 o rows <1024, partials >=1024
    attn_kernel<<<dim3(32, 24), 256, 0, stream>>>(
        qbuf, kbuf, vtbuf, embT, obuf, Opart, Lpart);

    // 3b. merge split-K partials for rows >= 1024
    merge_kernel<<<2048, 256, 0, stream>>>(Opart, Lpart, obuf);

    // 4. output projection (fp32 out)
    mfma_gemm<0><<<dim3(8, 32), 256, 0, stream>>>(
        obuf, wt_out, DMODEL, out_scale, out_bias, (float*)d_out,
        nullptr, nullptr, nullptr, nullptr, nullptr, nullptr, 0.0f);
}